// Round 9
// baseline (174.663 us; speedup 1.0000x reference)
//
#include <hip/hip_runtime.h>
#include <hip/hip_bf16.h>
#include <hip/hip_fp16.h>

typedef _Float16 half8 __attribute__((ext_vector_type(8)));
typedef _Float16 half4 __attribute__((ext_vector_type(4)));
typedef float floatx4 __attribute__((ext_vector_type(4)));

#define BATCH   4096
#define NIN     1024
#define NODES   4095
#define NPAD    4096
#define NOUT    1024
#define NLEAF   4096
#define SPLITK  4

__device__ __forceinline__ void gload_lds16(const void* g, void* l) {
    __builtin_amdgcn_global_load_lds(
        (const __attribute__((address_space(1))) void*)g,
        (__attribute__((address_space(3))) void*)l, 16, 0, 0);
}

// hardware barrier + full compiler memory fence, NO implicit waitcnt drain
#define BAR() asm volatile("s_barrier" ::: "memory")

// ---------- convert f32 -> f16, zero-padding past nsrc ----------
__global__ void k_f32_to_f16_pad(const float* __restrict__ src,
                                 _Float16* __restrict__ dst, int n, int nsrc) {
    int i = (blockIdx.x * blockDim.x + threadIdx.x) * 4;
    if (i >= n) return;
    float4 v;
    if (i < nsrc) v = *(const float4*)(src + i);
    else          v = make_float4(0.f, 0.f, 0.f, 0.f);
    half4 h;
    h.x = (_Float16)v.x; h.y = (_Float16)v.y;
    h.z = (_Float16)v.z; h.w = (_Float16)v.w;
    *(half4*)(dst + i) = h;
}

// ---------- transpose leaf [NLEAF][NOUT] f32 -> leafT [NOUT][NLEAF] f16 ----------
__global__ void k_transpose_f16(const float* __restrict__ src,
                                _Float16* __restrict__ dst) {
    __shared__ _Float16 t[32][33];
    int l0 = blockIdx.x * 32, o0 = blockIdx.y * 32;
    int tx = threadIdx.x & 31, ty = threadIdx.x >> 5;  // 32 x 8
#pragma unroll
    for (int i = 0; i < 4; i++) {
        int l = l0 + ty + i * 8;
        t[ty + i * 8][tx] = (_Float16)src[(size_t)l * NOUT + o0 + tx];
    }
    __syncthreads();
#pragma unroll
    for (int i = 0; i < 4; i++) {
        int o = o0 + ty + i * 8;
        dst[(size_t)o * NLEAF + l0 + tx] = t[tx][ty + i * 8];
    }
}

// ============ 256x256 modulo-scheduled GEMM (C = A * B^T), f16 MFMA ============
// 8 waves (2M x 4N), per-wave output 128x64, INTERLEAVED rows:
//   rows = qr*128 + wm*64 + fr*16, cols = qc*128 + wn*32 + fc*16.
// SOFTWARE PIPELINE (read one phase AHEAD, so MFMA never waits on same-phase DS):
//   P1: MFMA q00<af0,bf0c>; read bf1[T]    (4 b128); stage (T+1).Ah1; gate; BAR
//   P2: MFMA q01<af0,bf1 >; read af1[T]    (8);      stage (T+2).Bh0; BAR
//   P3: MFMA q11<af1,bf1 >; read bf0n[T+1] (4);      stage (T+2).Ah0; gate; BAR
//   P4: MFMA q10<af1,bf0c>; read af0[T+1]  (8);      stage (T+2).Bh1; BAR
//   rotate bf0c <- bf0n.   Reads balanced 4/8/4/8; DS ~576 cyc/phase avg
//   overlaps MFMA ~620 cyc/phase instead of serializing.
// HAZARD LEDGER (buffer b(T)=T&1; stages target b(T+2)=buf):
//   overwrite vs last-read separation (cross-wave safe: each read's consumer
//   MFMA forces lgkm retirement before the barrier preceding the stage):
//     Bs[buf][0]: read prev-P3, consumed P1 -> staged P2 (1 barrier)  OK
//     As[buf][0]: read prev-P4, consumed P1/P2 -> staged P3           OK
//     Bs[buf][1]: read P1, consumed P2 -> staged P4                   OK
//     As[buf][1]: read P2, consumed P3 -> staged next-P1              OK
//   gates (vmcnt counts 2 loads/half): end-P1 vmcnt(4) leaves {(T+1).Bh1,Ah1}
//     -> forces (T+1).Bh0/Ah0 for P3/P4 reads; end-P3 vmcnt(4) leaves
//     {(T+2).Bh0,Ah0} -> forces (T+1).Bh1/Ah1 for next-P1/P2 reads.
// LDS chunk swizzle (both-sides, rule 21): chunk c of row r at pos c^(r&7);
// write side via pre-swizzled GLOBAL source (LDS dest linear), read same XOR.
// EPILOGUE==1: C fp16 = sigmoid(acc + bias[col])   (gate GEMM)
// EPILOGUE==2: C fp16 partial at C + z*M*ldc       (leaf GEMM split-K)
#define MFMA_CL(QR, QC, AARR, BARRV, KK)                                        \
  _Pragma("unroll") for (int fr = 0; fr < 4; fr++)                              \
    _Pragma("unroll") for (int fc = 0; fc < 2; fc++)                            \
      acc[QR][QC][fr][fc] = __builtin_amdgcn_mfma_f32_16x16x32_f16(             \
          AARR[fr][KK], BARRV[fc][KK], acc[QR][QC][fr][fc], 0, 0, 0);

template <int EPILOGUE>
__launch_bounds__(512, 2)
__global__ void gemm256(const _Float16* __restrict__ A,
                        const _Float16* __restrict__ Bm,
                        const float* __restrict__ bias,
                        void* __restrict__ C,
                        int M, int N, int K, int ldc, int Klen) {
    __shared__ __align__(16) _Float16 As[2][2][128 * 64];
    __shared__ __align__(16) _Float16 Bs[2][2][128 * 64];
    const int tid  = threadIdx.x;
    const int lane = tid & 63;
    const int wid  = tid >> 6;       // 0..7
    const int wm   = wid >> 2;       // 0..1
    const int wn   = wid & 3;        // 0..3
    const int m0 = blockIdx.y * 256;
    const int n0 = blockIdx.x * 256;
    const int k0 = blockIdx.z * Klen;
    (void)N;

    floatx4 acc[2][2][4][2] = {};
    half8 af0[4][2];   // A quadrant qr=0 of tile T (read prev-iter P4)
    half8 af1[4][2];   // A quadrant qr=1 of tile T (read P2)
    half8 bf0c[2][2];  // B quadrant qc=0 of tile T (rotated in)
    half8 bf0n[2][2];  // B quadrant qc=0 of tile T+1 (read P3)
    half8 bf1[2][2];   // B quadrant qc=1 of tile T (read P1)

    // ---- staging geometry: thread stages 16B chunk tid (r=tid>>3,pos=tid&7)
    // and chunk tid+512 (row+64, same pos); source chunk pre-swizzled c=pos^(r&7).
    const int r1 = tid >> 3;
    const int c1 = (tid & 7) ^ (r1 & 7);
    const _Float16* Abase = A  + (size_t)(m0 + r1) * K + k0 + c1 * 8;
    const _Float16* Bbase = Bm + (size_t)(n0 + r1) * K + k0 + c1 * 8;

    auto stageA = [&](int bufx, int h, int T) {
        const _Float16* s = Abase + (size_t)h * 128 * K + T * 64;
        gload_lds16(s,                    &As[bufx][h][tid * 8]);
        gload_lds16(s + (size_t)64 * K,   &As[bufx][h][4096 + tid * 8]);
    };
    auto stageB = [&](int bufx, int h, int T) {
        const _Float16* s = Bbase + (size_t)h * 128 * K + T * 64;
        gload_lds16(s,                    &Bs[bufx][h][tid * 8]);
        gload_lds16(s + (size_t)64 * K,   &Bs[bufx][h][4096 + tid * 8]);
    };

    // ---- ds_read geometry: fragment row reads chunk c = kk*4 + (lane>>4)
    // at swizzled pos (c ^ (row&7)); row&7 invariant across fr (fr*16 % 8 == 0).
    const int l4   = lane >> 4;
    const int arow = wm * 64 + (lane & 15);
    const int brow = wn * 32 + (lane & 15);
    const int pA0 = ((l4)     ^ (arow & 7)) * 8;
    const int pA1 = ((4 + l4) ^ (arow & 7)) * 8;
    const int pB0 = ((l4)     ^ (brow & 7)) * 8;
    const int pB1 = ((4 + l4) ^ (brow & 7)) * 8;

    const int NTt = Klen >> 6;

    // ---- prologue: stage tile0 {Bh0,Ah0,Bh1,Ah1} + tile1 {Bh0,Ah0,Bh1};
    // vmcnt(6) forces tile0's 4 halves landed (leaves tile1's 3 in flight).
    stageB(0, 0, 0); stageA(0, 0, 0); stageB(0, 1, 0); stageA(0, 1, 0);
    if (NTt > 1) {
        stageB(1, 0, 1); stageA(1, 0, 1); stageB(1, 1, 1);
        asm volatile("s_waitcnt vmcnt(6)" ::: "memory");
    } else {
        asm volatile("s_waitcnt vmcnt(0)" ::: "memory");
    }
    BAR();
    // preload tile0's first operands: af0 = A[0][qr0], bf0c = B[0][qc0]
#pragma unroll
    for (int fr = 0; fr < 4; fr++) {
        af0[fr][0] = *(const half8*)(&As[0][0][(arow + fr * 16) * 64 + pA0]);
        af0[fr][1] = *(const half8*)(&As[0][0][(arow + fr * 16) * 64 + pA1]);
    }
#pragma unroll
    for (int fc = 0; fc < 2; fc++) {
        bf0c[fc][0] = *(const half8*)(&Bs[0][0][(brow + fc * 16) * 64 + pB0]);
        bf0c[fc][1] = *(const half8*)(&Bs[0][0][(brow + fc * 16) * 64 + pB1]);
    }

    for (int T = 0; T < NTt; ++T) {
        const int buf = T & 1;
        const _Float16* A_c = &As[buf][0][0];
        const _Float16* B_c = &Bs[buf][0][0];
        const _Float16* A_n = &As[buf ^ 1][0][0];
        const _Float16* B_n = &Bs[buf ^ 1][0][0];

        // ======== P1: MFMA q00; read bf1[T]; stage (T+1).Ah1; gate
#pragma unroll
        for (int fc = 0; fc < 2; fc++) {
            bf1[fc][0] = *(const half8*)(B_c + 8192 + (brow + fc * 16) * 64 + pB0);
            bf1[fc][1] = *(const half8*)(B_c + 8192 + (brow + fc * 16) * 64 + pB1);
        }
        if (T + 1 < NTt) stageA(buf ^ 1, 1, T + 1);
        __builtin_amdgcn_s_setprio(1);
        MFMA_CL(0, 0, af0, bf0c, 0);
        MFMA_CL(0, 0, af0, bf0c, 1);
        __builtin_amdgcn_s_setprio(0);
        if (T + 1 < NTt) {
            if (T + 2 < NTt) asm volatile("s_waitcnt vmcnt(4)" ::: "memory");
            else             asm volatile("s_waitcnt vmcnt(0)" ::: "memory");
        }
        BAR();

        // ======== P2: MFMA q01; read af1[T]; stage (T+2).Bh0
#pragma unroll
        for (int fr = 0; fr < 4; fr++) {
            af1[fr][0] = *(const half8*)(A_c + 8192 + (arow + fr * 16) * 64 + pA0);
            af1[fr][1] = *(const half8*)(A_c + 8192 + (arow + fr * 16) * 64 + pA1);
        }
        if (T + 2 < NTt) stageB(buf, 0, T + 2);
        __builtin_amdgcn_s_setprio(1);
        MFMA_CL(0, 1, af0, bf1, 0);
        MFMA_CL(0, 1, af0, bf1, 1);
        __builtin_amdgcn_s_setprio(0);
        BAR();

        // ======== P3: MFMA q11; read bf0n[T+1]; stage (T+2).Ah0; gate
        if (T + 1 < NTt) {
#pragma unroll
            for (int fc = 0; fc < 2; fc++) {
                bf0n[fc][0] = *(const half8*)(B_n + (brow + fc * 16) * 64 + pB0);
                bf0n[fc][1] = *(const half8*)(B_n + (brow + fc * 16) * 64 + pB1);
            }
        }
        if (T + 2 < NTt) stageA(buf, 0, T + 2);
        __builtin_amdgcn_s_setprio(1);
        MFMA_CL(1, 1, af1, bf1, 0);
        MFMA_CL(1, 1, af1, bf1, 1);
        __builtin_amdgcn_s_setprio(0);
        if (T + 1 < NTt) {
            if (T + 2 < NTt) asm volatile("s_waitcnt vmcnt(4)" ::: "memory");
            else             asm volatile("s_waitcnt vmcnt(0)" ::: "memory");
        }
        BAR();

        // ======== P4: MFMA q10; read af0[T+1]; stage (T+2).Bh1
        if (T + 1 < NTt) {
#pragma unroll
            for (int fr = 0; fr < 4; fr++) {
                af0[fr][0] = *(const half8*)(A_n + (arow + fr * 16) * 64 + pA0);
                af0[fr][1] = *(const half8*)(A_n + (arow + fr * 16) * 64 + pA1);
            }
        }
        if (T + 2 < NTt) stageB(buf, 1, T + 2);
        __builtin_amdgcn_s_setprio(1);
        MFMA_CL(1, 0, af1, bf0c, 0);
        MFMA_CL(1, 0, af1, bf0c, 1);
        __builtin_amdgcn_s_setprio(0);
        BAR();

        // rotate B qc0 operands
#pragma unroll
        for (int fc = 0; fc < 2; fc++) {
            bf0c[fc][0] = bf0n[fc][0];
            bf0c[fc][1] = bf0n[fc][1];
        }
    }

    // ---- epilogue: C/D layout col=lane&15, row=(lane>>4)*4+rj
    const int erow = m0 + wm * 64 + l4 * 4;
    const int ecol = n0 + wn * 32 + (lane & 15);
    _Float16* Cp = (_Float16*)C + (EPILOGUE == 2 ? (size_t)blockIdx.z * M * ldc : 0);
#pragma unroll
    for (int qr = 0; qr < 2; qr++)
#pragma unroll
        for (int qc = 0; qc < 2; qc++)
#pragma unroll
            for (int fr = 0; fr < 4; fr++)
#pragma unroll
                for (int fc = 0; fc < 2; fc++) {
                    const int col = ecol + qc * 128 + fc * 16;
#pragma unroll
                    for (int rj = 0; rj < 4; rj++) {
                        const int row = erow + qr * 128 + fr * 16 + rj;
                        float v = acc[qr][qc][fr][fc][rj];
                        if (EPILOGUE == 1) {
                            float bb = (col < NODES) ? bias[col] : 0.f;
                            float z = v + bb;
                            Cp[(size_t)row * ldc + col] =
                                (_Float16)(1.f / (1.f + __expf(-z)));
                        } else {
                            Cp[(size_t)row * ldc + col] = (_Float16)v;
                        }
                    }
                }
}

// ---------- reduce 4 fp16 partials -> f32 out ----------
__global__ void k_reduce4(const _Float16* __restrict__ part, float* __restrict__ out) {
    const size_t S = (size_t)BATCH * NOUT;
    size_t i = ((size_t)blockIdx.x * 256 + threadIdx.x) * 8;
    half8 a = *(const half8*)(part + i);
    half8 b = *(const half8*)(part + S + i);
    half8 c = *(const half8*)(part + 2 * S + i);
    half8 d = *(const half8*)(part + 3 * S + i);
    float4 lo, hi;
    lo.x = (float)a[0] + (float)b[0] + (float)c[0] + (float)d[0];
    lo.y = (float)a[1] + (float)b[1] + (float)c[1] + (float)d[1];
    lo.z = (float)a[2] + (float)b[2] + (float)c[2] + (float)d[2];
    lo.w = (float)a[3] + (float)b[3] + (float)c[3] + (float)d[3];
    hi.x = (float)a[4] + (float)b[4] + (float)c[4] + (float)d[4];
    hi.y = (float)a[5] + (float)b[5] + (float)c[5] + (float)d[5];
    hi.z = (float)a[6] + (float)b[6] + (float)c[6] + (float)d[6];
    hi.w = (float)a[7] + (float)b[7] + (float)c[7] + (float)d[7];
    *(float4*)(out + i) = lo;
    *(float4*)(out + i + 4) = hi;
}

// ---------- probs: per batch row, hierarchical tree-product expansion ----------
__global__ void k_probs(const _Float16* __restrict__ g,
                        _Float16* __restrict__ probs) {
    __shared__ float gs[NPAD];
    const int b = blockIdx.x;
    const _Float16* grow = g + (size_t)b * NPAD;
#pragma unroll
    for (int it = 0; it < 2; it++) {
        int i = threadIdx.x + it * 256;   // i in [0,512): 8 halves each
        half8 v = *(const half8*)(grow + i * 8);
#pragma unroll
        for (int j = 0; j < 8; j++) gs[i * 8 + j] = (float)v[j];
    }
    __syncthreads();
    const int t = threadIdx.x;  // subtree over leaves [t*16, t*16+16)
    float p = 1.f;
#pragma unroll
    for (int d = 0; d < 8; d++) {
        int node = (1 << d) - 1 + (t >> (8 - d));
        float gg = gs[node];
        int bit = (t >> (7 - d)) & 1;
        p *= bit ? gg : (1.f - gg);
    }
    float p9[2], p10[4], p11[8], p12[16];
    {
        float gg = gs[255 + t];
        p9[0] = p * (1.f - gg); p9[1] = p * gg;
    }
#pragma unroll
    for (int i = 0; i < 2; i++) {
        float gg = gs[511 + 2 * t + i];
        p10[2 * i] = p9[i] * (1.f - gg); p10[2 * i + 1] = p9[i] * gg;
    }
#pragma unroll
    for (int i = 0; i < 4; i++) {
        float gg = gs[1023 + 4 * t + i];
        p11[2 * i] = p10[i] * (1.f - gg); p11[2 * i + 1] = p10[i] * gg;
    }
#pragma unroll
    for (int i = 0; i < 8; i++) {
        float gg = gs[2047 + 8 * t + i];
        p12[2 * i] = p11[i] * (1.f - gg); p12[2 * i + 1] = p11[i] * gg;
    }
    half8 o0, o1;
#pragma unroll
    for (int j = 0; j < 8; j++) { o0[j] = (_Float16)p12[j]; o1[j] = (_Float16)p12[8 + j]; }
    _Float16* pr = probs + (size_t)b * NLEAF + t * 16;
    *(half8*)(pr) = o0;
    *(half8*)(pr + 8) = o1;
}

extern "C" void kernel_launch(void* const* d_in, const int* in_sizes, int n_in,
                              void* d_out, int out_size, void* d_ws, size_t ws_size,
                              hipStream_t stream) {
    (void)in_sizes; (void)n_in; (void)out_size; (void)ws_size;
    const float* x    = (const float*)d_in[0];
    const float* W    = (const float*)d_in[1];
    const float* bias = (const float*)d_in[2];
    const float* leaf = (const float*)d_in[3];
    float* out = (float*)d_out;

    // ws layout (halves). Long-lived first; partials alias the dead region.
    _Float16* base  = (_Float16*)d_ws;
    _Float16* leafT = base;                                   // [0,8) MB   live: transpose -> leaf GEMM
    _Float16* probs = base + (size_t)4 * 1024 * 1024;         // [8,40) MB  live: k_probs -> leaf GEMM
    _Float16* xh    = base + (size_t)20 * 1024 * 1024;        // [40,48) MB dead after gate GEMM
    _Float16* Wh    = base + (size_t)24 * 1024 * 1024;        // [48,56) MB dead after gate GEMM
    _Float16* g     = base + (size_t)28 * 1024 * 1024;        // [56,88) MB dead after k_probs
    _Float16* part  = xh;                                     // [40,72) MB written by leaf GEMM (after k_probs)

    k_f32_to_f16_pad<<<(BATCH * NIN / 4 + 255) / 256, 256, 0, stream>>>(
        x, xh, BATCH * NIN, BATCH * NIN);
    k_f32_to_f16_pad<<<(NPAD * NIN / 4 + 255) / 256, 256, 0, stream>>>(
        W, Wh, NPAD * NIN, NODES * NIN);
    k_transpose_f16<<<dim3(NLEAF / 32, NOUT / 32), 256, 0, stream>>>(leaf, leafT);

    gemm256<1><<<dim3(NPAD / 256, BATCH / 256, 1), 512, 0, stream>>>(
        xh, Wh, bias, (void*)g, BATCH, NPAD, NIN, NPAD, NIN);

    k_probs<<<BATCH, 256, 0, stream>>>(g, probs);

    gemm256<2><<<dim3(NOUT / 256, BATCH / 256, SPLITK), 512, 0, stream>>>(
        probs, leafT, nullptr, (void*)part, BATCH, NOUT, NLEAF, NOUT, NLEAF / SPLITK);

    k_reduce4<<<(BATCH * NOUT) / (256 * 8), 256, 0, stream>>>(part, out);
}

// Round 10
// 129.222 us; speedup vs baseline: 1.3517x; 1.3517x over previous
//
#include <hip/hip_runtime.h>
#include <hip/hip_bf16.h>
#include <hip/hip_fp16.h>

typedef _Float16 half8 __attribute__((ext_vector_type(8)));
typedef _Float16 half4 __attribute__((ext_vector_type(4)));
typedef float floatx4 __attribute__((ext_vector_type(4)));

#define BATCH   4096
#define NIN     1024
#define NODES   4095
#define NPAD    4096
#define NOUT    1024
#define NLEAF   4096
#define SPLITK  4

__device__ __forceinline__ void gload_lds16(const void* g, void* l) {
    __builtin_amdgcn_global_load_lds(
        (const __attribute__((address_space(1))) void*)g,
        (__attribute__((address_space(3))) void*)l, 16, 0, 0);
}

// hardware barrier + full compiler memory fence, NO implicit waitcnt drain
#define BAR() asm volatile("s_barrier" ::: "memory")

// ---------- convert f32 -> f16, zero-padding past nsrc ----------
__global__ void k_f32_to_f16_pad(const float* __restrict__ src,
                                 _Float16* __restrict__ dst, int n, int nsrc) {
    int i = (blockIdx.x * blockDim.x + threadIdx.x) * 4;
    if (i >= n) return;
    float4 v;
    if (i < nsrc) v = *(const float4*)(src + i);
    else          v = make_float4(0.f, 0.f, 0.f, 0.f);
    half4 h;
    h.x = (_Float16)v.x; h.y = (_Float16)v.y;
    h.z = (_Float16)v.z; h.w = (_Float16)v.w;
    *(half4*)(dst + i) = h;
}

// ---------- transpose leaf [NLEAF][NOUT] f32 -> leafT [NOUT][NLEAF] f16 ----------
__global__ void k_transpose_f16(const float* __restrict__ src,
                                _Float16* __restrict__ dst) {
    __shared__ _Float16 t[32][33];
    int l0 = blockIdx.x * 32, o0 = blockIdx.y * 32;
    int tx = threadIdx.x & 31, ty = threadIdx.x >> 5;  // 32 x 8
#pragma unroll
    for (int i = 0; i < 4; i++) {
        int l = l0 + ty + i * 8;
        t[ty + i * 8][tx] = (_Float16)src[(size_t)l * NOUT + o0 + tx];
    }
    __syncthreads();
#pragma unroll
    for (int i = 0; i < 4; i++) {
        int o = o0 + ty + i * 8;
        dst[(size_t)o * NLEAF + l0 + tx] = t[tx][ty + i * 8];
    }
}

// ============ 256x256 2-phase GEMM (C = A * B^T), f16 MFMA ============
// 8 waves (2M x 4N), per-wave output 128x64, INTERLEAVED rows:
//   rows = qr*128 + wm*64 + fr*16, cols = qc*128 + wn*32 + fc*16.
// TWO phases per K-tile-of-64 (was 4): halves the barrier count; each phase
// has 32 MFMA to amortize the barrier-resync + LDS-latency ramp.
//   P1: read af0(8 b128)+bf0(4)+bf1(4); stage (T+1).Ah1,(T+1).Bh0 -> buf^1;
//       MFMA q00+q01 (32); BAR
//   P2: read af1(8, reusing af regs); stage (T+2).Ah0,(T+2).Bh1 -> buf;
//       MFMA q11+q10 (32, bf0/bf1 held in regs); gate; BAR
// Gate at end P2: vmcnt(4) == T+2's 4 loads in flight, forces all of tile
// T+1 landed before its first read at T+1 P1.
// HAZARD LEDGER (single-bar phases; a read is retired before the MFMA that
// consumes it, which precedes that phase's barrier):
//   P1 stage Ah1(T+1)->buf^1: last read T-1 P2 (af1), consumed there; >=1 bar.
//   P1 stage Bh0(T+1)->buf^1: last read T-1 P1 (bf0), consumed by T-1 P2 MFMA
//     before T-1 P2's BAR; stage is after that BAR.
//   P2 stage Ah0(T+2)->buf: read this iter P1 (af0), consumed by P1 MFMA
//     before P1's BAR; stage after it.
//   P2 stage Bh1(T+2)->buf: bf1 read in P1, already in registers; other
//     waves' reads retired before the shared P1 BAR.
// LDS chunk swizzle (both-sides, rule 21): chunk c of row r at pos c^(r&7);
// write side via pre-swizzled GLOBAL source (LDS dest linear), read same XOR.
// EPILOGUE==1: C fp16 = sigmoid(acc + bias[col])   (gate GEMM)
// EPILOGUE==2: C fp16 partial at C + z*M*ldc       (leaf GEMM split-K)
#define MFMA_CL(QR, QC, AARR, BARRV, KK)                                        \
  _Pragma("unroll") for (int fr = 0; fr < 4; fr++)                              \
    _Pragma("unroll") for (int fc = 0; fc < 2; fc++)                            \
      acc[QR][QC][fr][fc] = __builtin_amdgcn_mfma_f32_16x16x32_f16(             \
          AARR[fr][KK], BARRV[fc][KK], acc[QR][QC][fr][fc], 0, 0, 0);

template <int EPILOGUE>
__launch_bounds__(512, 2)
__global__ void gemm256(const _Float16* __restrict__ A,
                        const _Float16* __restrict__ Bm,
                        const float* __restrict__ bias,
                        void* __restrict__ C,
                        int M, int N, int K, int ldc, int Klen) {
    __shared__ __align__(16) _Float16 As[2][2][128 * 64];
    __shared__ __align__(16) _Float16 Bs[2][2][128 * 64];
    const int tid  = threadIdx.x;
    const int lane = tid & 63;
    const int wid  = tid >> 6;       // 0..7
    const int wm   = wid >> 2;       // 0..1
    const int wn   = wid & 3;        // 0..3
    const int m0 = blockIdx.y * 256;
    const int n0 = blockIdx.x * 256;
    const int k0 = blockIdx.z * Klen;
    (void)N;

    floatx4 acc[2][2][4][2] = {};

    // ---- staging geometry: thread stages 16B chunk tid (r=tid>>3,pos=tid&7)
    // and chunk tid+512 (row+64, same pos); source chunk pre-swizzled c=pos^(r&7).
    const int r1 = tid >> 3;
    const int c1 = (tid & 7) ^ (r1 & 7);
    const _Float16* Abase = A  + (size_t)(m0 + r1) * K + k0 + c1 * 8;
    const _Float16* Bbase = Bm + (size_t)(n0 + r1) * K + k0 + c1 * 8;

    auto stageA = [&](int bufx, int h, int T) {
        const _Float16* s = Abase + (size_t)h * 128 * K + T * 64;
        gload_lds16(s,                    &As[bufx][h][tid * 8]);
        gload_lds16(s + (size_t)64 * K,   &As[bufx][h][4096 + tid * 8]);
    };
    auto stageB = [&](int bufx, int h, int T) {
        const _Float16* s = Bbase + (size_t)h * 128 * K + T * 64;
        gload_lds16(s,                    &Bs[bufx][h][tid * 8]);
        gload_lds16(s + (size_t)64 * K,   &Bs[bufx][h][4096 + tid * 8]);
    };

    // ---- ds_read geometry: fragment row reads chunk c = kk*4 + (lane>>4)
    // at swizzled pos (c ^ (row&7)); row&7 invariant across fr (fr*16 % 8 == 0).
    const int l4   = lane >> 4;
    const int arow = wm * 64 + (lane & 15);
    const int brow = wn * 32 + (lane & 15);
    const int pA0 = ((l4)     ^ (arow & 7)) * 8;
    const int pA1 = ((4 + l4) ^ (arow & 7)) * 8;
    const int pB0 = ((l4)     ^ (brow & 7)) * 8;
    const int pB1 = ((4 + l4) ^ (brow & 7)) * 8;

    const int NTt = Klen >> 6;

    // ---- prologue: tile0 fully + tile1's {Ah0,Bh1}; leave tile1's pair in flight
    stageA(0, 0, 0); stageB(0, 0, 0); stageA(0, 1, 0); stageB(0, 1, 0);
    if (NTt > 1) {
        stageA(1, 0, 1); stageB(1, 1, 1);
        asm volatile("s_waitcnt vmcnt(4)" ::: "memory");
    } else {
        asm volatile("s_waitcnt vmcnt(0)" ::: "memory");
    }
    BAR();

    for (int T = 0; T < NTt; ++T) {
        const int buf = T & 1;
        const _Float16* A0 = &As[buf][0][0];
        const _Float16* A1 = &As[buf][1][0];
        const _Float16* B0 = &Bs[buf][0][0];
        const _Float16* B1 = &Bs[buf][1][0];

        half8 af[4][2];    // A quadrant fragments (qr0 in P1, reloaded qr1 in P2)
        half8 bf0[2][2];   // B quadrant qc=0 (read P1, used P1.q00 & P2.q10)
        half8 bf1[2][2];   // B quadrant qc=1 (read P1, used P1.q01 & P2.q11)

        // ======== P1: reads af0(8)+bf0(4)+bf1(4); stage (T+1).{Ah1,Bh0}; 32 MFMA
#pragma unroll
        for (int fr = 0; fr < 4; fr++) {
            af[fr][0] = *(const half8*)(A0 + (arow + fr * 16) * 64 + pA0);
            af[fr][1] = *(const half8*)(A0 + (arow + fr * 16) * 64 + pA1);
        }
#pragma unroll
        for (int fc = 0; fc < 2; fc++) {
            bf0[fc][0] = *(const half8*)(B0 + (brow + fc * 16) * 64 + pB0);
            bf0[fc][1] = *(const half8*)(B0 + (brow + fc * 16) * 64 + pB1);
            bf1[fc][0] = *(const half8*)(B1 + (brow + fc * 16) * 64 + pB0);
            bf1[fc][1] = *(const half8*)(B1 + (brow + fc * 16) * 64 + pB1);
        }
        if (T + 1 < NTt) { stageA(buf ^ 1, 1, T + 1); stageB(buf ^ 1, 0, T + 1); }
        __builtin_amdgcn_s_setprio(1);
        MFMA_CL(0, 0, af, bf0, 0);
        MFMA_CL(0, 0, af, bf0, 1);
        MFMA_CL(0, 1, af, bf1, 0);
        MFMA_CL(0, 1, af, bf1, 1);
        __builtin_amdgcn_s_setprio(0);
        BAR();

        // ======== P2: reads af1(8, reuse regs); stage (T+2).{Ah0,Bh1}; 32 MFMA; gate
#pragma unroll
        for (int fr = 0; fr < 4; fr++) {
            af[fr][0] = *(const half8*)(A1 + (arow + fr * 16) * 64 + pA0);
            af[fr][1] = *(const half8*)(A1 + (arow + fr * 16) * 64 + pA1);
        }
        if (T + 2 < NTt) { stageA(buf, 0, T + 2); stageB(buf, 1, T + 2); }
        __builtin_amdgcn_s_setprio(1);
        MFMA_CL(1, 1, af, bf1, 0);
        MFMA_CL(1, 1, af, bf1, 1);
        MFMA_CL(1, 0, af, bf0, 0);
        MFMA_CL(1, 0, af, bf0, 1);
        __builtin_amdgcn_s_setprio(0);
        if (T + 1 < NTt) {
            if (T + 2 < NTt) asm volatile("s_waitcnt vmcnt(4)" ::: "memory");
            else             asm volatile("s_waitcnt vmcnt(0)" ::: "memory");
        }
        BAR();
    }

    // ---- epilogue: C/D layout col=lane&15, row=(lane>>4)*4+rj
    const int erow = m0 + wm * 64 + l4 * 4;
    const int ecol = n0 + wn * 32 + (lane & 15);
    _Float16* Cp = (_Float16*)C + (EPILOGUE == 2 ? (size_t)blockIdx.z * M * ldc : 0);
#pragma unroll
    for (int qr = 0; qr < 2; qr++)
#pragma unroll
        for (int qc = 0; qc < 2; qc++)
#pragma unroll
            for (int fr = 0; fr < 4; fr++)
#pragma unroll
                for (int fc = 0; fc < 2; fc++) {
                    const int col = ecol + qc * 128 + fc * 16;
#pragma unroll
                    for (int rj = 0; rj < 4; rj++) {
                        const int row = erow + qr * 128 + fr * 16 + rj;
                        float v = acc[qr][qc][fr][fc][rj];
                        if (EPILOGUE == 1) {
                            float bb = (col < NODES) ? bias[col] : 0.f;
                            float z = v + bb;
                            Cp[(size_t)row * ldc + col] =
                                (_Float16)(1.f / (1.f + __expf(-z)));
                        } else {
                            Cp[(size_t)row * ldc + col] = (_Float16)v;
                        }
                    }
                }
}

// ---------- reduce 4 fp16 partials -> f32 out ----------
__global__ void k_reduce4(const _Float16* __restrict__ part, float* __restrict__ out) {
    const size_t S = (size_t)BATCH * NOUT;
    size_t i = ((size_t)blockIdx.x * 256 + threadIdx.x) * 8;
    half8 a = *(const half8*)(part + i);
    half8 b = *(const half8*)(part + S + i);
    half8 c = *(const half8*)(part + 2 * S + i);
    half8 d = *(const half8*)(part + 3 * S + i);
    float4 lo, hi;
    lo.x = (float)a[0] + (float)b[0] + (float)c[0] + (float)d[0];
    lo.y = (float)a[1] + (float)b[1] + (float)c[1] + (float)d[1];
    lo.z = (float)a[2] + (float)b[2] + (float)c[2] + (float)d[2];
    lo.w = (float)a[3] + (float)b[3] + (float)c[3] + (float)d[3];
    hi.x = (float)a[4] + (float)b[4] + (float)c[4] + (float)d[4];
    hi.y = (float)a[5] + (float)b[5] + (float)c[5] + (float)d[5];
    hi.z = (float)a[6] + (float)b[6] + (float)c[6] + (float)d[6];
    hi.w = (float)a[7] + (float)b[7] + (float)c[7] + (float)d[7];
    *(float4*)(out + i) = lo;
    *(float4*)(out + i + 4) = hi;
}

// ---------- probs: per batch row, hierarchical tree-product expansion ----------
__global__ void k_probs(const _Float16* __restrict__ g,
                        _Float16* __restrict__ probs) {
    __shared__ float gs[NPAD];
    const int b = blockIdx.x;
    const _Float16* grow = g + (size_t)b * NPAD;
#pragma unroll
    for (int it = 0; it < 2; it++) {
        int i = threadIdx.x + it * 256;   // i in [0,512): 8 halves each
        half8 v = *(const half8*)(grow + i * 8);
#pragma unroll
        for (int j = 0; j < 8; j++) gs[i * 8 + j] = (float)v[j];
    }
    __syncthreads();
    const int t = threadIdx.x;  // subtree over leaves [t*16, t*16+16)
    float p = 1.f;
#pragma unroll
    for (int d = 0; d < 8; d++) {
        int node = (1 << d) - 1 + (t >> (8 - d));
        float gg = gs[node];
        int bit = (t >> (7 - d)) & 1;
        p *= bit ? gg : (1.f - gg);
    }
    float p9[2], p10[4], p11[8], p12[16];
    {
        float gg = gs[255 + t];
        p9[0] = p * (1.f - gg); p9[1] = p * gg;
    }
#pragma unroll
    for (int i = 0; i < 2; i++) {
        float gg = gs[511 + 2 * t + i];
        p10[2 * i] = p9[i] * (1.f - gg); p10[2 * i + 1] = p9[i] * gg;
    }
#pragma unroll
    for (int i = 0; i < 4; i++) {
        float gg = gs[1023 + 4 * t + i];
        p11[2 * i] = p10[i] * (1.f - gg); p11[2 * i + 1] = p10[i] * gg;
    }
#pragma unroll
    for (int i = 0; i < 8; i++) {
        float gg = gs[2047 + 8 * t + i];
        p12[2 * i] = p11[i] * (1.f - gg); p12[2 * i + 1] = p11[i] * gg;
    }
    half8 o0, o1;
#pragma unroll
    for (int j = 0; j < 8; j++) { o0[j] = (_Float16)p12[j]; o1[j] = (_Float16)p12[8 + j]; }
    _Float16* pr = probs + (size_t)b * NLEAF + t * 16;
    *(half8*)(pr) = o0;
    *(half8*)(pr + 8) = o1;
}

extern "C" void kernel_launch(void* const* d_in, const int* in_sizes, int n_in,
                              void* d_out, int out_size, void* d_ws, size_t ws_size,
                              hipStream_t stream) {
    (void)in_sizes; (void)n_in; (void)out_size; (void)ws_size;
    const float* x    = (const float*)d_in[0];
    const float* W    = (const float*)d_in[1];
    const float* bias = (const float*)d_in[2];
    const float* leaf = (const float*)d_in[3];
    float* out = (float*)d_out;

    // ws layout (halves). Long-lived first; partials alias the dead region.
    _Float16* base  = (_Float16*)d_ws;
    _Float16* leafT = base;                                   // [0,8) MB   live: transpose -> leaf GEMM
    _Float16* probs = base + (size_t)4 * 1024 * 1024;         // [8,40) MB  live: k_probs -> leaf GEMM
    _Float16* xh    = base + (size_t)20 * 1024 * 1024;        // [40,48) MB dead after gate GEMM
    _Float16* Wh    = base + (size_t)24 * 1024 * 1024;        // [48,56) MB dead after gate GEMM
    _Float16* g     = base + (size_t)28 * 1024 * 1024;        // [56,88) MB dead after k_probs
    _Float16* part  = xh;                                     // [40,72) MB written by leaf GEMM (after k_probs)

    k_f32_to_f16_pad<<<(BATCH * NIN / 4 + 255) / 256, 256, 0, stream>>>(
        x, xh, BATCH * NIN, BATCH * NIN);
    k_f32_to_f16_pad<<<(NPAD * NIN / 4 + 255) / 256, 256, 0, stream>>>(
        W, Wh, NPAD * NIN, NODES * NIN);
    k_transpose_f16<<<dim3(NLEAF / 32, NOUT / 32), 256, 0, stream>>>(leaf, leafT);

    gemm256<1><<<dim3(NPAD / 256, BATCH / 256, 1), 512, 0, stream>>>(
        xh, Wh, bias, (void*)g, BATCH, NPAD, NIN, NPAD, NIN);

    k_probs<<<BATCH, 256, 0, stream>>>(g, probs);

    gemm256<2><<<dim3(NOUT / 256, BATCH / 256, SPLITK), 512, 0, stream>>>(
        probs, leafT, nullptr, (void*)part, BATCH, NOUT, NLEAF, NOUT, NLEAF / SPLITK);

    k_reduce4<<<(BATCH * NOUT) / (256 * 8), 256, 0, stream>>>(part, out);
}

// Round 11
// 124.654 us; speedup vs baseline: 1.4012x; 1.0366x over previous
//
#include <hip/hip_runtime.h>
#include <hip/hip_bf16.h>
#include <hip/hip_fp16.h>

typedef _Float16 half8 __attribute__((ext_vector_type(8)));
typedef _Float16 half4 __attribute__((ext_vector_type(4)));
typedef float floatx4 __attribute__((ext_vector_type(4)));
typedef float floatx16 __attribute__((ext_vector_type(16)));

#define BATCH   4096
#define NIN     1024
#define NODES   4095
#define NPAD    4096
#define NOUT    1024
#define NLEAF   4096
#define SPLITK  4

__device__ __forceinline__ void gload_lds16(const void* g, void* l) {
    __builtin_amdgcn_global_load_lds(
        (const __attribute__((address_space(1))) void*)g,
        (__attribute__((address_space(3))) void*)l, 16, 0, 0);
}

// ---------- convert f32 -> f16, zero-padding past nsrc ----------
__global__ void k_f32_to_f16_pad(const float* __restrict__ src,
                                 _Float16* __restrict__ dst, int n, int nsrc) {
    int i = (blockIdx.x * blockDim.x + threadIdx.x) * 4;
    if (i >= n) return;
    float4 v;
    if (i < nsrc) v = *(const float4*)(src + i);
    else          v = make_float4(0.f, 0.f, 0.f, 0.f);
    half4 h;
    h.x = (_Float16)v.x; h.y = (_Float16)v.y;
    h.z = (_Float16)v.z; h.w = (_Float16)v.w;
    *(half4*)(dst + i) = h;
}

// ---------- transpose leaf [NLEAF][NOUT] f32 -> leafT [NOUT][NLEAF] f16 ----------
__global__ void k_transpose_f16(const float* __restrict__ src,
                                _Float16* __restrict__ dst) {
    __shared__ _Float16 t[32][33];
    int l0 = blockIdx.x * 32, o0 = blockIdx.y * 32;
    int tx = threadIdx.x & 31, ty = threadIdx.x >> 5;  // 32 x 8
#pragma unroll
    for (int i = 0; i < 4; i++) {
        int l = l0 + ty + i * 8;
        t[ty + i * 8][tx] = (_Float16)src[(size_t)l * NOUT + o0 + tx];
    }
    __syncthreads();
#pragma unroll
    for (int i = 0; i < 4; i++) {
        int o = o0 + ty + i * 8;
        dst[(size_t)o * NLEAF + l0 + tx] = t[tx][ty + i * 8];
    }
}

// ======== 256x256 16-wave TLP GEMM (C = A * B^T), 32x32x16 f16 MFMA ========
// R5-R10 lesson: 8 barrier-locked waves = 2/SIMD leave ~50% of cycles with no
// pipe issuing (lockstep: both waves read together, then MFMA together). This
// version restores TLP (Guideline 1 / m114 mechanism): 16 waves = 4/SIMD,
// per-wave 64x64 output, mfma_32x32x16 (16 MFMA/K-tile/wave, acc 4x16 f32 =
// 64 VGPR -> fits the 128-VGPR budget 4 waves/SIMD requires).
// Loop = m97-proven shape: stage tile T+1 at top of iter T (4 gload_lds16 per
// thread, 1024 thr x 16B = one 128x64 half-tile per call), kk-split ds_reads
// (4 b128 per kk step of 16), 16 MFMA, ONE __syncthreads per K-tile (drain is
// cheap: stages issued a full iteration earlier; TLP covers the rest).
// Wave (wm,wn) reads only A-half wm>>1 and B-half wn>>1 (rows wm*64+i*32+lane31
// never cross the 128-row half boundary).
// LDS chunk swizzle (both-sides, rule 21): chunk c of row r at pos c^(r&7);
// write side via pre-swizzled GLOBAL source (LDS dest linear), read same XOR;
// read pos = (kk*2 + (lane>>5)) ^ (lane&7) -- row&7 == lane&7 invariant.
// EPILOGUE==1: C fp16 = sigmoid(acc + bias[col])   (gate GEMM)
// EPILOGUE==2: C fp16 partial at C + z*M*ldc       (leaf GEMM split-K)
// C/D layout (32x32, m74/m101): col = lane&31, row = (r&3)+8*(r>>2)+4*(lane>>5).
template <int EPILOGUE>
__launch_bounds__(1024, 4)
__global__ void gemm256(const _Float16* __restrict__ A,
                        const _Float16* __restrict__ Bm,
                        const float* __restrict__ bias,
                        void* __restrict__ C,
                        int M, int N, int K, int ldc, int Klen) {
    __shared__ __align__(16) _Float16 As[2][2][128 * 64];
    __shared__ __align__(16) _Float16 Bs[2][2][128 * 64];
    const int tid  = threadIdx.x;
    const int lane = tid & 63;
    const int wid  = tid >> 6;       // 0..15
    const int wm   = wid >> 2;       // 0..3
    const int wn   = wid & 3;        // 0..3
    const int m0 = blockIdx.y * 256;
    const int n0 = blockIdx.x * 256;
    const int k0 = blockIdx.z * Klen;
    (void)N;

    floatx16 acc[2][2] = {};

    // ---- staging geometry: 1024 threads x 16B = one 128x64 half-tile/call.
    // thread covers chunk (r1 = tid>>3, pos = tid&7); source chunk pre-swizzled
    // c = pos ^ (r1&7) so LDS dest stays linear (rule 21).
    const int r1 = tid >> 3;
    const int c1 = (tid & 7) ^ (r1 & 7);
    const _Float16* Abase = A  + (size_t)(m0 + r1) * K + k0 + c1 * 8;
    const _Float16* Bbase = Bm + (size_t)(n0 + r1) * K + k0 + c1 * 8;

    auto stageA = [&](int bufx, int h, int T) {
        gload_lds16(Abase + (size_t)h * 128 * K + T * 64, &As[bufx][h][tid * 8]);
    };
    auto stageB = [&](int bufx, int h, int T) {
        gload_lds16(Bbase + (size_t)h * 128 * K + T * 64, &Bs[bufx][h][tid * 8]);
    };

    // ---- read geometry: wave reads A-half wm>>1 rows (wm&1)*64+i*32+(lane&31),
    // B-half wn>>1 rows (wn&1)*64+j*32+(lane&31); chunk c = kk*2 + (lane>>5),
    // swizzled pos = c ^ (lane&7).
    const int l5  = lane >> 5;
    const int l31 = lane & 31;
    const int ra  = (wm & 1) * 64 + l31;   // + i*32
    const int rb  = (wn & 1) * 64 + l31;   // + j*32
    const int ah  = wm >> 1;
    const int bh  = wn >> 1;
#define POSK(KK) ((((KK) * 2 + l5) ^ (lane & 7)) * 8)

    const int NTt = Klen >> 6;

    // ---- prologue: stage tile 0 into buf 0
    stageA(0, 0, 0); stageA(0, 1, 0); stageB(0, 0, 0); stageB(0, 1, 0);
    __syncthreads();

    int buf = 0;
    for (int T = 0; T < NTt; ++T) {
        if (T + 1 < NTt) {   // stage next tile into the other buffer
            stageA(buf ^ 1, 0, T + 1); stageA(buf ^ 1, 1, T + 1);
            stageB(buf ^ 1, 0, T + 1); stageB(buf ^ 1, 1, T + 1);
        }
        const _Float16* Ab = &As[buf][ah][0];
        const _Float16* Bb = &Bs[buf][bh][0];
#pragma unroll
        for (int kk = 0; kk < 4; kk++) {
            const int pos = POSK(kk);
            half8 a0 = *(const half8*)(Ab + (ra)      * 64 + pos);
            half8 a1 = *(const half8*)(Ab + (ra + 32) * 64 + pos);
            half8 b0 = *(const half8*)(Bb + (rb)      * 64 + pos);
            half8 b1 = *(const half8*)(Bb + (rb + 32) * 64 + pos);
            acc[0][0] = __builtin_amdgcn_mfma_f32_32x32x16_f16(a0, b0, acc[0][0], 0, 0, 0);
            acc[0][1] = __builtin_amdgcn_mfma_f32_32x32x16_f16(a0, b1, acc[0][1], 0, 0, 0);
            acc[1][0] = __builtin_amdgcn_mfma_f32_32x32x16_f16(a1, b0, acc[1][0], 0, 0, 0);
            acc[1][1] = __builtin_amdgcn_mfma_f32_32x32x16_f16(a1, b1, acc[1][1], 0, 0, 0);
        }
        __syncthreads();  // drains next-tile stage + this tile's reads
        buf ^= 1;
    }

    // ---- epilogue: 32x32 C/D layout col=lane&31, row=(r&3)+8*(r>>2)+4*l5
    _Float16* Cp = (_Float16*)C + (EPILOGUE == 2 ? (size_t)blockIdx.z * M * ldc : 0);
#pragma unroll
    for (int i = 0; i < 2; i++)
#pragma unroll
        for (int j = 0; j < 2; j++) {
            const int col = n0 + wn * 64 + j * 32 + l31;
            float bb = 0.f;
            if (EPILOGUE == 1) bb = (col < NODES) ? bias[col] : 0.f;
#pragma unroll
            for (int r = 0; r < 16; r++) {
                const int row = m0 + wm * 64 + i * 32 + (r & 3) + 8 * (r >> 2) + 4 * l5;
                float v = acc[i][j][r];
                if (EPILOGUE == 1) {
                    float z = v + bb;
                    Cp[(size_t)row * ldc + col] = (_Float16)(1.f / (1.f + __expf(-z)));
                } else {
                    Cp[(size_t)row * ldc + col] = (_Float16)v;
                }
            }
        }
#undef POSK
}

// ---------- reduce 4 fp16 partials -> f32 out ----------
__global__ void k_reduce4(const _Float16* __restrict__ part, float* __restrict__ out) {
    const size_t S = (size_t)BATCH * NOUT;
    size_t i = ((size_t)blockIdx.x * 256 + threadIdx.x) * 8;
    half8 a = *(const half8*)(part + i);
    half8 b = *(const half8*)(part + S + i);
    half8 c = *(const half8*)(part + 2 * S + i);
    half8 d = *(const half8*)(part + 3 * S + i);
    float4 lo, hi;
    lo.x = (float)a[0] + (float)b[0] + (float)c[0] + (float)d[0];
    lo.y = (float)a[1] + (float)b[1] + (float)c[1] + (float)d[1];
    lo.z = (float)a[2] + (float)b[2] + (float)c[2] + (float)d[2];
    lo.w = (float)a[3] + (float)b[3] + (float)c[3] + (float)d[3];
    hi.x = (float)a[4] + (float)b[4] + (float)c[4] + (float)d[4];
    hi.y = (float)a[5] + (float)b[5] + (float)c[5] + (float)d[5];
    hi.z = (float)a[6] + (float)b[6] + (float)c[6] + (float)d[6];
    hi.w = (float)a[7] + (float)b[7] + (float)c[7] + (float)d[7];
    *(float4*)(out + i) = lo;
    *(float4*)(out + i + 4) = hi;
}

// ---------- probs: per batch row, hierarchical tree-product expansion ----------
__global__ void k_probs(const _Float16* __restrict__ g,
                        _Float16* __restrict__ probs) {
    __shared__ float gs[NPAD];
    const int b = blockIdx.x;
    const _Float16* grow = g + (size_t)b * NPAD;
#pragma unroll
    for (int it = 0; it < 2; it++) {
        int i = threadIdx.x + it * 256;   // i in [0,512): 8 halves each
        half8 v = *(const half8*)(grow + i * 8);
#pragma unroll
        for (int j = 0; j < 8; j++) gs[i * 8 + j] = (float)v[j];
    }
    __syncthreads();
    const int t = threadIdx.x;  // subtree over leaves [t*16, t*16+16)
    float p = 1.f;
#pragma unroll
    for (int d = 0; d < 8; d++) {
        int node = (1 << d) - 1 + (t >> (8 - d));
        float gg = gs[node];
        int bit = (t >> (7 - d)) & 1;
        p *= bit ? gg : (1.f - gg);
    }
    float p9[2], p10[4], p11[8], p12[16];
    {
        float gg = gs[255 + t];
        p9[0] = p * (1.f - gg); p9[1] = p * gg;
    }
#pragma unroll
    for (int i = 0; i < 2; i++) {
        float gg = gs[511 + 2 * t + i];
        p10[2 * i] = p9[i] * (1.f - gg); p10[2 * i + 1] = p9[i] * gg;
    }
#pragma unroll
    for (int i = 0; i < 4; i++) {
        float gg = gs[1023 + 4 * t + i];
        p11[2 * i] = p10[i] * (1.f - gg); p11[2 * i + 1] = p10[i] * gg;
    }
#pragma unroll
    for (int i = 0; i < 8; i++) {
        float gg = gs[2047 + 8 * t + i];
        p12[2 * i] = p11[i] * (1.f - gg); p12[2 * i + 1] = p11[i] * gg;
    }
    half8 o0, o1;
#pragma unroll
    for (int j = 0; j < 8; j++) { o0[j] = (_Float16)p12[j]; o1[j] = (_Float16)p12[8 + j]; }
    _Float16* pr = probs + (size_t)b * NLEAF + t * 16;
    *(half8*)(pr) = o0;
    *(half8*)(pr + 8) = o1;
}

extern "C" void kernel_launch(void* const* d_in, const int* in_sizes, int n_in,
                              void* d_out, int out_size, void* d_ws, size_t ws_size,
                              hipStream_t stream) {
    (void)in_sizes; (void)n_in; (void)out_size; (void)ws_size;
    const float* x    = (const float*)d_in[0];
    const float* W    = (const float*)d_in[1];
    const float* bias = (const float*)d_in[2];
    const float* leaf = (const float*)d_in[3];
    float* out = (float*)d_out;

    // ws layout (halves). Long-lived first; partials alias the dead region.
    _Float16* base  = (_Float16*)d_ws;
    _Float16* leafT = base;                                   // [0,8) MB   live: transpose -> leaf GEMM
    _Float16* probs = base + (size_t)4 * 1024 * 1024;         // [8,40) MB  live: k_probs -> leaf GEMM
    _Float16* xh    = base + (size_t)20 * 1024 * 1024;        // [40,48) MB dead after gate GEMM
    _Float16* Wh    = base + (size_t)24 * 1024 * 1024;        // [48,56) MB dead after gate GEMM
    _Float16* g     = base + (size_t)28 * 1024 * 1024;        // [56,88) MB dead after k_probs
    _Float16* part  = xh;                                     // [40,72) MB written by leaf GEMM (after k_probs)

    k_f32_to_f16_pad<<<(BATCH * NIN / 4 + 255) / 256, 256, 0, stream>>>(
        x, xh, BATCH * NIN, BATCH * NIN);
    k_f32_to_f16_pad<<<(NPAD * NIN / 4 + 255) / 256, 256, 0, stream>>>(
        W, Wh, NPAD * NIN, NODES * NIN);
    k_transpose_f16<<<dim3(NLEAF / 32, NOUT / 32), 256, 0, stream>>>(leaf, leafT);

    gemm256<1><<<dim3(NPAD / 256, BATCH / 256, 1), 1024, 0, stream>>>(
        xh, Wh, bias, (void*)g, BATCH, NPAD, NIN, NPAD, NIN);

    k_probs<<<BATCH, 256, 0, stream>>>(g, probs);

    gemm256<2><<<dim3(NOUT / 256, BATCH / 256, SPLITK), 1024, 0, stream>>>(
        probs, leafT, nullptr, (void*)part, BATCH, NOUT, NLEAF, NOUT, NLEAF / SPLITK);

    k_reduce4<<<(BATCH * NOUT) / (256 * 8), 256, 0, stream>>>(part, out);
}